// Round 5
// baseline (37.283 us; speedup 1.0000x reference)
//
#include <hip/hip_runtime.h>

// Fused elastic wave time step (seistorch), B=4, NZ=NX=1024, f32.
// Barrier-free, LDS-free: one block = one full x-row (256 thr x float4),
// marching an R=8 strip in z. Velocity needs fresh stress at x+4 / x-1 in the
// same row -> fetched from the neighbor lane via __shfl; wave-boundary lanes
// (0 / 63) compute that one halo stress column redundantly from predicated
// scalar loads. z-1 stress terms roll in registers. Circular wrap via &(N-1).

constexpr int Bn = 4, NZ = 1024, NX = 1024;
constexpr int PLANE = NZ * NX;
constexpr int NPTS = Bn * PLANE;
constexpr int R = 8;                 // rows per strip
constexpr int NSTRIP = NZ / R;       // 128
constexpr int LOG_NSTRIP = 7;

__global__ __launch_bounds__(256) void fused_wave_kernel(
    const float* __restrict__ vp, const float* __restrict__ vs,
    const float* __restrict__ rho, const float* __restrict__ vx,
    const float* __restrict__ vz, const float* __restrict__ txx,
    const float* __restrict__ tzz, const float* __restrict__ txz,
    const float* __restrict__ dtp, const float* __restrict__ hp,
    const float* __restrict__ dpml,
    float* __restrict__ y_vx, float* __restrict__ y_vz,
    float* __restrict__ y_txx, float* __restrict__ y_tzz,
    float* __restrict__ y_txz)
{
    const int tid = threadIdx.x;
    const int lane = tid & 63;
    const int x0 = tid * 4;
    const int xm1 = (x0 - 1) & (NX - 1);
    const int xp4 = (x0 + 4) & (NX - 1);
    const int strip = blockIdx.x & (NSTRIP - 1);
    const int b = blockIdx.x >> LOG_NSTRIP;
    const int z0 = strip * R;
    const size_t fb = (size_t)b * PLANE;

    const float dt = dtp[0], h = hp[0];
    const float dth = dt / h;

    // ---- prologue: vx/vz row z0-1 ----
    const int r0 = (z0 - 1) & (NZ - 1);
    const size_t rb0 = fb + (size_t)r0 * NX;
    float4 cvx = *(const float4*)(vx + rb0 + x0);
    float4 cvz = *(const float4*)(vz + rb0 + x0);
    float  cvxm = vx[rb0 + xm1];
    float  cvzp = vz[rb0 + xp4];
    float  cvxp = 0.f, cvzm = 0.f;
    if (lane == 63) cvxp = vx[rb0 + xp4];
    if (lane == 0)  cvzm = vz[rb0 + xm1];

    float p_tzz[4] = {0, 0, 0, 0};
    float p_txz[4] = {0, 0, 0, 0};

#pragma unroll
    for (int k = 0; k <= R; ++k) {
        const int r  = (z0 - 1 + k) & (NZ - 1);
        const int rp = (r + 1) & (NZ - 1);
        const size_t rowb  = fb + (size_t)r * NX;
        const size_t rowbp = fb + (size_t)rp * NX;
        const int mrow = r * NX;

        // row r+1 vx/vz (needed by stress row r), row r materials + old stress
        float4 nvx = *(const float4*)(vx + rowbp + x0);
        float4 nvz = *(const float4*)(vz + rowbp + x0);
        float  nvxm = vx[rowbp + xm1];
        float  nvzp = vz[rowbp + xp4];
        float  nvxp = 0.f, nvzm = 0.f;
        float4 ctxx = *(const float4*)(txx + rowb + x0);
        float4 ctzz = *(const float4*)(tzz + rowb + x0);
        float4 ctxz = *(const float4*)(txz + rowb + x0);
        float4 cvp = *(const float4*)(vp + mrow + x0);
        float4 cvs = *(const float4*)(vs + mrow + x0);
        float4 crh = *(const float4*)(rho + mrow + x0);
        float4 cd  = *(const float4*)(dpml + mrow + x0);

        // halo-lane extras
        float txxh_o = 0.f, vph = 0.f, vsh = 0.f, rhh = 0.f, dh = 0.f;
        float txzh_o = 0.f, vsl = 0.f, rhl = 0.f, dl = 0.f;
        if (lane == 63) {
            nvxp   = vx[rowbp + xp4];
            txxh_o = txx[rowb + xp4];
            vph = vp[mrow + xp4]; vsh = vs[mrow + xp4];
            rhh = rho[mrow + xp4]; dh = dpml[mrow + xp4];
        }
        if (lane == 0) {
            nvzm   = vz[rowbp + xm1];
            txzh_o = txz[rowb + xm1];
            vsl = vs[mrow + xm1]; rhl = rho[mrow + xm1];
            dl = dpml[mrow + xm1];
        }

        // ---- own stress row r ----
        float fvx[5]  = {cvxm, cvx.x, cvx.y, cvx.z, cvx.w};
        float fvz[5]  = {cvz.x, cvz.y, cvz.z, cvz.w, cvzp};
        float fvx1[4] = {nvx.x, nvx.y, nvx.z, nvx.w};
        float fvz1[4] = {nvz.x, nvz.y, nvz.z, nvz.w};
        float ftxxo[4] = {ctxx.x, ctxx.y, ctxx.z, ctxx.w};
        float ftzzo[4] = {ctzz.x, ctzz.y, ctzz.z, ctzz.w};
        float ftxzo[4] = {ctxz.x, ctxz.y, ctxz.z, ctxz.w};
        float fvp[4] = {cvp.x, cvp.y, cvp.z, cvp.w};
        float fvs[4] = {cvs.x, cvs.y, cvs.z, cvs.w};
        float frh[4] = {crh.x, crh.y, crh.z, crh.w};
        float fd[4]  = {cd.x, cd.y, cd.z, cd.w};

        float o_txx[4], o_tzz[4], o_txz[4], inv[4], omc[4];
#pragma unroll
        for (int i = 0; i < 4; ++i) {
            float lam = frh[i] * (fvp[i] * fvp[i] - 2.0f * fvs[i] * fvs[i]);
            float mu  = frh[i] * fvs[i] * fvs[i];
            float vx_x = fvx[i + 1] - fvx[i];     // vx[x] - vx[x-1]
            float vz_z = fvz1[i] - fvz[i];        // vz[z+1] - vz[z]
            float vx_z = fvx1[i] - fvx[i + 1];    // vx[z+1] - vx[z]
            float vz_x = fvz[i + 1] - fvz[i];     // vz[x+1] - vz[x]
            float c = 0.5f * dt * fd[i];
            inv[i] = 1.0f / (1.0f + c);
            omc[i] = 1.0f - c;
            float lp2m = lam + 2.0f * mu;
            o_txx[i] = inv[i] * (dth * (lp2m * vx_x + lam * vz_z) + omc[i] * ftxxo[i]);
            o_tzz[i] = inv[i] * (dth * (lp2m * vz_z + lam * vx_x) + omc[i] * ftzzo[i]);
            o_txz[i] = inv[i] * (dth * mu * (vz_x + vx_z) + omc[i] * ftxzo[i]);
        }

        // ---- redundant halo stresses (used only on lanes 63 / 0) ----
        float txxh, txzh;
        {   // lane 63: txx at column x0+4, row r
            float lamh = rhh * (vph * vph - 2.0f * vsh * vsh);
            float muh  = rhh * vsh * vsh;
            float vxxh = cvxp - cvx.w;       // vx[x+4] - vx[x+3]
            float vzzh = nvzp - cvzp;        // vz[z+1,x+4] - vz[z,x+4]
            float ch = 0.5f * dt * dh;
            txxh = (1.0f / (1.0f + ch)) *
                   (dth * ((lamh + 2.0f * muh) * vxxh + lamh * vzzh) +
                    (1.0f - ch) * txxh_o);
        }
        {   // lane 0: txz at column x0-1, row r
            float mul = rhl * vsl * vsl;
            float vzxl = cvz.x - cvzm;       // vz[x0] - vz[x0-1]
            float vxzl = nvxm - cvxm;        // vx[z+1,x0-1] - vx[z,x0-1]
            float cl = 0.5f * dt * dl;
            txzh = (1.0f / (1.0f + cl)) *
                   (dth * mul * (vzxl + vxzl) + (1.0f - cl) * txzh_o);
        }

        float txxp4 = __shfl_down(o_txx[0], 1);
        float txzm1 = __shfl_up(o_txz[3], 1);
        if (lane == 63) txxp4 = txxh;
        if (lane == 0)  txzm1 = txzh;

        if (k > 0) {
            *(float4*)(y_txx + rowb + x0) = make_float4(o_txx[0], o_txx[1], o_txx[2], o_txx[3]);
            *(float4*)(y_tzz + rowb + x0) = make_float4(o_tzz[0], o_tzz[1], o_tzz[2], o_tzz[3]);
            *(float4*)(y_txz + rowb + x0) = make_float4(o_txz[0], o_txz[1], o_txz[2], o_txz[3]);

            float ftxx5[5] = {o_txx[0], o_txx[1], o_txx[2], o_txx[3], txxp4};
            float ftxz5[5] = {txzm1, o_txz[0], o_txz[1], o_txz[2], o_txz[3]};
            float fvxc[4] = {cvx.x, cvx.y, cvx.z, cvx.w};
            float fvzc[4] = {cvz.x, cvz.y, cvz.z, cvz.w};

            float o_vx[4], o_vz[4];
#pragma unroll
            for (int i = 0; i < 4; ++i) {
                float txx_x = ftxx5[i + 1] - ftxx5[i];   // txx[x+1]-txx[x]
                float txz_z = ftxz5[i + 1] - p_txz[i];   // txz[z]-txz[z-1]
                float tzz_z = o_tzz[i] - p_tzz[i];       // tzz[z]-tzz[z-1]
                float txz_x = ftxz5[i + 1] - ftxz5[i];   // txz[x]-txz[x-1]
                float s = dth / frh[i];
                o_vx[i] = inv[i] * (s * (txx_x + txz_z) + omc[i] * fvxc[i]);
                o_vz[i] = inv[i] * (s * (txz_x + tzz_z) + omc[i] * fvzc[i]);
            }
            *(float4*)(y_vx + rowb + x0) = make_float4(o_vx[0], o_vx[1], o_vx[2], o_vx[3]);
            *(float4*)(y_vz + rowb + x0) = make_float4(o_vz[0], o_vz[1], o_vz[2], o_vz[3]);
        }

        // ---- roll ----
        cvx = nvx; cvz = nvz;
        cvxm = nvxm; cvzp = nvzp;
        cvxp = nvxp; cvzm = nvzm;
#pragma unroll
        for (int i = 0; i < 4; ++i) { p_tzz[i] = o_tzz[i]; p_txz[i] = o_txz[i]; }
    }
}

extern "C" void kernel_launch(void* const* d_in, const int* in_sizes, int n_in,
                              void* d_out, int out_size, void* d_ws, size_t ws_size,
                              hipStream_t stream) {
    const float* vp  = (const float*)d_in[0];
    const float* vs  = (const float*)d_in[1];
    const float* rho = (const float*)d_in[2];
    const float* vx  = (const float*)d_in[3];
    const float* vz  = (const float*)d_in[4];
    const float* txx = (const float*)d_in[5];
    const float* tzz = (const float*)d_in[6];
    const float* txz = (const float*)d_in[7];
    const float* dtp = (const float*)d_in[8];
    const float* hp  = (const float*)d_in[9];
    const float* dpm = (const float*)d_in[10];

    float* out   = (float*)d_out;
    float* y_vx  = out;
    float* y_vz  = out + (size_t)NPTS;
    float* y_txx = out + 2 * (size_t)NPTS;
    float* y_tzz = out + 3 * (size_t)NPTS;
    float* y_txz = out + 4 * (size_t)NPTS;

    dim3 block(256);
    dim3 grid(Bn * NSTRIP);   // 512 blocks
    fused_wave_kernel<<<grid, block, 0, stream>>>(vp, vs, rho, vx, vz, txx, tzz, txz,
                                                  dtp, hp, dpm,
                                                  y_vx, y_vz, y_txx, y_tzz, y_txz);
}